// Round 3
// baseline (316.577 us; speedup 1.0000x reference)
//
#include <hip/hip_runtime.h>
#include <hip/hip_bf16.h>

// Problem constants (B=4, T=4096, D=1024). All inputs/outputs are FP32
// (per the reference); bf16 is used internally for MFMA only.
#define BB 4
#define TT 4096
#define DD 1024
#define MM (BB * TT)   // 16384 rows
#define LN_EPS 1e-5f

typedef __attribute__((ext_vector_type(8))) short bf16x8;   // 8 bf16 = 4 VGPRs
typedef __attribute__((ext_vector_type(4))) float f32x4;

__device__ __forceinline__ float bfbits2f(unsigned short h) {
    return __uint_as_float(((unsigned int)h) << 16);
}
__device__ __forceinline__ unsigned short f2bfbits(float f) {
    __hip_bfloat16 h = __float2bfloat16(f);
    return *reinterpret_cast<unsigned short*>(&h);
}

// async global->LDS, 16B per lane. HW: wave-uniform LDS base + lane*16.
// Slot layout (slot = r*256+tid, offset slot*16B) satisfies this.
__device__ __forceinline__ void async_copy16(void* lds, const void* g) {
    __builtin_amdgcn_global_load_lds(
        (const __attribute__((address_space(1))) void*)g,
        (__attribute__((address_space(3))) void*)lds,
        16, 0, 0);
}

// ---------------------------------------------------------------------------
// fp32 -> bf16 weight conversion: [1024x1024], 1024 blocks x 256 thr x 4.
// ---------------------------------------------------------------------------
__global__ __launch_bounds__(256)
void convert_w(const float* __restrict__ src, __hip_bfloat16* __restrict__ dst)
{
    const size_t i = ((size_t)blockIdx.x * 256 + threadIdx.x) * 4;
    float4 v = *(const float4*)(src + i);
    ushort4 o;
    o.x = f2bfbits(v.x);
    o.y = f2bfbits(v.y);
    o.z = f2bfbits(v.z);
    o.w = f2bfbits(v.w);
    *(ushort4*)((unsigned short*)dst + i) = o;
}

// ---------------------------------------------------------------------------
// LayerNorm: fp32 in -> bf16 out. One block per row; 256 threads x 4 elems.
// ---------------------------------------------------------------------------
__global__ __launch_bounds__(256)
void ln_kernel(const float* __restrict__ x,
               const float* __restrict__ w,
               const float* __restrict__ b,
               __hip_bfloat16* __restrict__ out)
{
    const int row = blockIdx.x;
    const int tid = threadIdx.x;

    float4 v = *(const float4*)(x + (size_t)row * DD + tid * 4);

    float s  = v.x + v.y + v.z + v.w;
    float ss = fmaf(v.x, v.x, fmaf(v.y, v.y, fmaf(v.z, v.z, v.w * v.w)));

    #pragma unroll
    for (int o = 32; o > 0; o >>= 1) {
        s  += __shfl_down(s, o);
        ss += __shfl_down(ss, o);
    }

    __shared__ float red[8];
    const int wave = tid >> 6, lane = tid & 63;
    if (lane == 0) { red[wave] = s; red[4 + wave] = ss; }
    __syncthreads();
    s  = red[0] + red[1] + red[2] + red[3];
    ss = red[4] + red[5] + red[6] + red[7];

    const float mu   = s * (1.0f / DD);
    const float var  = ss * (1.0f / DD) - mu * mu;
    const float rstd = rsqrtf(var + LN_EPS);

    float4 wr = *(const float4*)(w + tid * 4);
    float4 br = *(const float4*)(b + tid * 4);

    ushort4 o4;
    o4.x = f2bfbits((v.x - mu) * rstd * wr.x + br.x);
    o4.y = f2bfbits((v.y - mu) * rstd * wr.y + br.y);
    o4.z = f2bfbits((v.z - mu) * rstd * wr.z + br.z);
    o4.w = f2bfbits((v.w - mu) * rstd * wr.w + br.w);
    *(ushort4*)((unsigned short*)out + (size_t)row * DD + tid * 4) = o4;
}

// ---------------------------------------------------------------------------
// Fused dual GEMM + gate:
//   g = A @ Wg^T + gb;  v = A @ Wv^T + vb;  U = (2*sigmoid(g)-1)*v
// A, Wg, Wv bf16 (torch Linear layout [out,in]); gb, vb fp32; U bf16.
// Tile 128x128, BK=32, 4 waves (2x2), each wave 64x64 per output.
// ---------------------------------------------------------------------------
__global__ __launch_bounds__(256, 2)
void dual_gemm_gate(const __hip_bfloat16* __restrict__ A,
                    const __hip_bfloat16* __restrict__ Wg,
                    const __hip_bfloat16* __restrict__ Wv,
                    const float* __restrict__ gb,
                    const float* __restrict__ vb,
                    __hip_bfloat16* __restrict__ U,
                    int M, int N, int K)
{
    constexpr int BK = 32;
    __shared__ short As[128 * BK];
    __shared__ short Bg[128 * BK];
    __shared__ short Bv[128 * BK];

    const int tid  = threadIdx.x;
    const int m0   = blockIdx.x * 128;
    const int n0   = blockIdx.y * 128;
    const int wave = tid >> 6;
    const int lane = tid & 63;
    const int wm   = (wave & 1) * 64;
    const int wn   = (wave >> 1) * 64;
    const int lrow = lane & 15;
    const int kgrp = lane >> 4;      // 0..3

    f32x4 accg[4][4] = {};
    f32x4 accv[4][4] = {};

    const int srow = tid >> 2;
    const int sc   = tid & 3;
    const __hip_bfloat16* ga0 = A  + (size_t)(m0 + srow) * K + sc * 8;
    const __hip_bfloat16* gg0 = Wg + (size_t)(n0 + srow) * K + sc * 8;
    const __hip_bfloat16* gv0 = Wv + (size_t)(n0 + srow) * K + sc * 8;

    for (int k0 = 0; k0 < K; k0 += BK) {
        #pragma unroll
        for (int r = 0; r < 2; ++r) {
            async_copy16(&As[(r * 256 + tid) * 8], ga0 + (size_t)r * 64 * K + k0);
            async_copy16(&Bg[(r * 256 + tid) * 8], gg0 + (size_t)r * 64 * K + k0);
            async_copy16(&Bv[(r * 256 + tid) * 8], gv0 + (size_t)r * 64 * K + k0);
        }
        __builtin_amdgcn_s_waitcnt(0);
        __syncthreads();

        bf16x8 af[4], bgf[4], bvf[4];
        #pragma unroll
        for (int i = 0; i < 4; ++i)
            af[i] = *(const bf16x8*)&As[(wm + i * 16 + lrow) * BK + kgrp * 8];
        #pragma unroll
        for (int j = 0; j < 4; ++j) {
            bgf[j] = *(const bf16x8*)&Bg[(wn + j * 16 + lrow) * BK + kgrp * 8];
            bvf[j] = *(const bf16x8*)&Bv[(wn + j * 16 + lrow) * BK + kgrp * 8];
        }

        #pragma unroll
        for (int i = 0; i < 4; ++i)
            #pragma unroll
            for (int j = 0; j < 4; ++j) {
                accg[i][j] = __builtin_amdgcn_mfma_f32_16x16x32_bf16(
                    af[i], bgf[j], accg[i][j], 0, 0, 0);
                accv[i][j] = __builtin_amdgcn_mfma_f32_16x16x32_bf16(
                    af[i], bvf[j], accv[i][j], 0, 0, 0);
            }
        __syncthreads();
    }

    // Epilogue. C/D layout: col = lane&15, row = (lane>>4)*4 + reg
    #pragma unroll
    for (int j = 0; j < 4; ++j) {
        const int col = n0 + wn + j * 16 + lrow;
        const float gbv = gb[col];
        const float vbv = vb[col];
        #pragma unroll
        for (int i = 0; i < 4; ++i) {
            #pragma unroll
            for (int r = 0; r < 4; ++r) {
                const int row = m0 + wm + i * 16 + kgrp * 4 + r;
                const float g = accg[i][j][r] + gbv;
                const float v = accv[i][j][r] + vbv;
                const float u = (2.0f / (1.0f + __expf(-g)) - 1.0f) * v;
                U[(size_t)row * N + col] = __float2bfloat16(u);
            }
        }
    }
}

// ---------------------------------------------------------------------------
// Final GEMM: out[m,n] = X[m,n] + sum_k S[m,k]*Wo[n,k] + ob[n]
// S, Wo bf16; X, ob, out fp32.
// ---------------------------------------------------------------------------
__global__ __launch_bounds__(256, 2)
void gemm_out(const __hip_bfloat16* __restrict__ A,
              const __hip_bfloat16* __restrict__ W,
              const float* __restrict__ bias,
              const float* __restrict__ X,
              float* __restrict__ C,
              int M, int N, int K)
{
    constexpr int BK = 32;
    __shared__ short As[128 * BK];
    __shared__ short Bs[128 * BK];

    const int tid  = threadIdx.x;
    const int m0   = blockIdx.x * 128;
    const int n0   = blockIdx.y * 128;
    const int wave = tid >> 6;
    const int lane = tid & 63;
    const int wm   = (wave & 1) * 64;
    const int wn   = (wave >> 1) * 64;
    const int lrow = lane & 15;
    const int kgrp = lane >> 4;

    f32x4 acc[4][4] = {};

    const int srow = tid >> 2;
    const int sc   = tid & 3;
    const __hip_bfloat16* ga0 = A + (size_t)(m0 + srow) * K + sc * 8;
    const __hip_bfloat16* gb0 = W + (size_t)(n0 + srow) * K + sc * 8;

    for (int k0 = 0; k0 < K; k0 += BK) {
        #pragma unroll
        for (int r = 0; r < 2; ++r) {
            async_copy16(&As[(r * 256 + tid) * 8], ga0 + (size_t)r * 64 * K + k0);
            async_copy16(&Bs[(r * 256 + tid) * 8], gb0 + (size_t)r * 64 * K + k0);
        }
        __builtin_amdgcn_s_waitcnt(0);
        __syncthreads();

        bf16x8 af[4], bfr[4];
        #pragma unroll
        for (int i = 0; i < 4; ++i)
            af[i] = *(const bf16x8*)&As[(wm + i * 16 + lrow) * BK + kgrp * 8];
        #pragma unroll
        for (int j = 0; j < 4; ++j)
            bfr[j] = *(const bf16x8*)&Bs[(wn + j * 16 + lrow) * BK + kgrp * 8];

        #pragma unroll
        for (int i = 0; i < 4; ++i)
            #pragma unroll
            for (int j = 0; j < 4; ++j)
                acc[i][j] = __builtin_amdgcn_mfma_f32_16x16x32_bf16(
                    af[i], bfr[j], acc[i][j], 0, 0, 0);
        __syncthreads();
    }

    #pragma unroll
    for (int j = 0; j < 4; ++j) {
        const int col = n0 + wn + j * 16 + lrow;
        const float bv = bias[col];
        #pragma unroll
        for (int i = 0; i < 4; ++i) {
            #pragma unroll
            for (int r = 0; r < 4; ++r) {
                const int row = m0 + wm + i * 16 + kgrp * 4 + r;
                const size_t idx = (size_t)row * N + col;
                C[idx] = acc[i][j][r] + bv + X[idx];
            }
        }
    }
}

// ---------------------------------------------------------------------------
// Scan over T, 3-phase. NC = 64 chunks of 64 timesteps. U bf16, Pk fp32.
// ---------------------------------------------------------------------------
#define NC 64
#define CL 64   // chunk length

__global__ __launch_bounds__(256)
void scan_partial(const __hip_bfloat16* __restrict__ U, float* __restrict__ Pk)
{
    const int c = blockIdx.x, b = blockIdx.y;
    const int d4 = threadIdx.x * 4;
    const unsigned short* p = (const unsigned short*)U +
        ((size_t)b * TT + (size_t)c * CL) * DD + d4;
    float s0 = 0, s1 = 0, s2 = 0, s3 = 0;
    #pragma unroll 16
    for (int t = 0; t < CL; ++t) {
        uint2 raw = *(const uint2*)(p + (size_t)t * DD);
        s0 += bfbits2f((unsigned short)(raw.x & 0xFFFF));
        s1 += bfbits2f((unsigned short)(raw.x >> 16));
        s2 += bfbits2f((unsigned short)(raw.y & 0xFFFF));
        s3 += bfbits2f((unsigned short)(raw.y >> 16));
    }
    *(float4*)&Pk[((size_t)b * NC + c) * DD + d4] = make_float4(s0, s1, s2, s3);
}

__global__ __launch_bounds__(256)
void scan_offsets(float* __restrict__ Pk)
{
    const int col4 = ((int)blockIdx.x * 256 + (int)threadIdx.x) * 4; // 0..4092
    const int b = col4 >> 10;
    const int d = col4 & 1023;
    float r0 = 0, r1 = 0, r2 = 0, r3 = 0;
    float* p = Pk + (size_t)b * NC * DD + d;
    #pragma unroll 8
    for (int c = 0; c < NC; ++c) {
        float4 v = *(float4*)(p + (size_t)c * DD);
        *(float4*)(p + (size_t)c * DD) = make_float4(r0, r1, r2, r3);
        r0 += v.x; r1 += v.y; r2 += v.z; r3 += v.w;
    }
}

__global__ __launch_bounds__(256)
void scan_final(const __hip_bfloat16* __restrict__ U,
                const float* __restrict__ Pk,
                const float* __restrict__ log_decay,
                __hip_bfloat16* __restrict__ S)
{
    const int c = blockIdx.x, b = blockIdx.y;
    const int d4 = threadIdx.x * 4;

    const float ld = log_decay[0];
    const float alpha = log1pf(__expf(ld));          // softplus
    const float ratio = __expf(-alpha);
    float dec = __expf(-alpha * (float)(c * CL));

    float4 run = *(const float4*)&Pk[((size_t)b * NC + c) * DD + d4];
    const size_t base = ((size_t)b * TT + (size_t)c * CL) * DD + d4;
    const unsigned short* up = (const unsigned short*)U + base;
    unsigned short* sp = (unsigned short*)S + base;

    #pragma unroll 16
    for (int t = 0; t < CL; ++t) {
        uint2 raw = *(const uint2*)(up + (size_t)t * DD);
        run.x += bfbits2f((unsigned short)(raw.x & 0xFFFF));
        run.y += bfbits2f((unsigned short)(raw.x >> 16));
        run.z += bfbits2f((unsigned short)(raw.y & 0xFFFF));
        run.w += bfbits2f((unsigned short)(raw.y >> 16));
        uint2 o;
        o.x = (unsigned int)f2bfbits(run.x * dec) |
              ((unsigned int)f2bfbits(run.y * dec) << 16);
        o.y = (unsigned int)f2bfbits(run.z * dec) |
              ((unsigned int)f2bfbits(run.w * dec) << 16);
        *(uint2*)(sp + (size_t)t * DD) = o;
        dec *= ratio;
    }
}

// ---------------------------------------------------------------------------
// Workspace: 39 MB. normed/S 32 MB | Pk 1 MB | Wg/Wv/Wo bf16 2 MB each.
// U (bf16, 32 MB) lives in d_out (fp32 64 MB); dead before gemm_out writes.
// ---------------------------------------------------------------------------
extern "C" void kernel_launch(void* const* d_in, const int* in_sizes, int n_in,
                              void* d_out, int out_size, void* d_ws, size_t ws_size,
                              hipStream_t stream)
{
    const float* x        = (const float*)d_in[0];
    const float* ln_w     = (const float*)d_in[1];
    const float* ln_b     = (const float*)d_in[2];
    const float* gate_w   = (const float*)d_in[3];
    const float* gate_b   = (const float*)d_in[4];
    const float* value_w  = (const float*)d_in[5];
    const float* value_b  = (const float*)d_in[6];
    const float* out_w    = (const float*)d_in[7];
    const float* out_b    = (const float*)d_in[8];
    const float* log_dec  = (const float*)d_in[9];
    float* out = (float*)d_out;

    char* ws = (char*)d_ws;
    const size_t MB = 1024 * 1024;
    __hip_bfloat16* normed = (__hip_bfloat16*)(ws);           // 32 MB, reused as S
    __hip_bfloat16* S      = (__hip_bfloat16*)(ws);
    float*          Pk     = (float*)(ws + 32 * MB);          // 1 MB
    __hip_bfloat16* Wg16   = (__hip_bfloat16*)(ws + 33 * MB); // 2 MB
    __hip_bfloat16* Wv16   = (__hip_bfloat16*)(ws + 35 * MB); // 2 MB
    __hip_bfloat16* Wo16   = (__hip_bfloat16*)(ws + 37 * MB); // 2 MB
    __hip_bfloat16* U      = (__hip_bfloat16*)d_out;          // scratch in d_out

    // 0. weight conversion fp32 -> bf16
    convert_w<<<dim3(1024), dim3(256), 0, stream>>>(gate_w,  Wg16);
    convert_w<<<dim3(1024), dim3(256), 0, stream>>>(value_w, Wv16);
    convert_w<<<dim3(1024), dim3(256), 0, stream>>>(out_w,   Wo16);

    // 1. LayerNorm: x -> normed (bf16)
    ln_kernel<<<dim3(MM), dim3(256), 0, stream>>>(x, ln_w, ln_b, normed);

    // 2. fused gate+value projections + gating: normed -> U (in d_out)
    dual_gemm_gate<<<dim3(MM / 128, DD / 128), dim3(256), 0, stream>>>(
        normed, Wg16, Wv16, gate_b, value_b, U, MM, DD, DD);

    // 3. decay-weighted cumsum over T: U -> S (overwrites normed; it's dead)
    scan_partial<<<dim3(NC, BB), dim3(256), 0, stream>>>(U, Pk);
    scan_offsets<<<dim3(4), dim3(256), 0, stream>>>(Pk);
    scan_final<<<dim3(NC, BB), dim3(256), 0, stream>>>(U, Pk, log_dec, S);

    // 4. out = x + S @ out_w^T + out_b   (overwrites U; it's dead)
    gemm_out<<<dim3(MM / 128, DD / 128), dim3(256), 0, stream>>>(
        S, Wo16, out_b, x, out, MM, DD, DD);
}